// Round 10
// baseline (266.095 us; speedup 1.0000x reference)
//
#include <hip/hip_runtime.h>
#include <hip/hip_cooperative_groups.h>
#include <stdint.h>

namespace cg = cooperative_groups;

// HashedEmbeddingBag: out[b][d] = sum_{i<50} weight[(idx[b][i]*P1 + d*P2) % WS]
// WS = 2,000,000; B = 16384; L = 50; D = 128.
//
// R19: single cooperative launch (conv fused via grid.sync) + R16 loop
// with the two R17-proven trims.
// Evidence: R16 plain loop (163.8us, VALU 87%) beats every unroll variant
// (R13 neutral, R17 233 broken-pipeline, R18 174.5 pipelined-but-select-
// chained) -> R16's 1-key-RT/iter body is the local optimum; unrolling
// retired. Remaining: (a) 47us gap between total (210.5) and kernels
// (163.8+~3 conv) = two serialized launches in the graph; (b) ~2-3
// ops/elem from diff-routing + K-space compare (accuracy-proven in
// R17/R18 at absmax 0.25, never isolated on the R16 shape).
//  - heb_fused: each block converts its 4096-entry fp32->bf16 slice
//    (512x4096 >= 2M), cg::this_grid().sync() (512 blocks exactly
//    co-resident: 2/CU, LDS 78.8KBx2, VGPR<=64), then R16 body.
//    Runtime fallback to conv+heb two-kernel path if coop launch fails.
//  - diff-routing: sa += v; so += (K&1)?v:0; epilogue even = sa-so.
//  - K-space condition: K < LIMK, LIMK = 2*(len+rlo)-C2 in (0,8M]
//    (sentinel 268M never passes); gather addr (K&~1)+CLr computed in
//    parallel with the compare -> shorter carried chain.
// Max key-read index rbase+200 < rbase+204 pad (loop reads +1 only).
// Geometry (R16-proven): 512 blocks x 32 bags, 16 pairs, SPT=2, 64KB
// tile, 62 regions, 76.75KB smem -> 2 blocks/CU, 8 waves/SIMD.

#define WS       2000000
#define EMB_DIM  128
#define BAG_LEN  50
#define BATCH    16384

#define NBLK     512
#define NTHR     1024
#define BPB      32                     // bags per block
#define NPAIR    16                     // bag-pair streams per block
#define SPT      2                      // streams per thread
#define EXTP     204                    // 100 + 100 rotation + 4 sentinels
#define TILEE    32768                  // tile entries (bf16) = 64KB
#define NREGS    62                     // 61*32768=1,998,848; last 1152
#define SBIG     300227u                // P2 % WS
#define SENT     0x10000000u            // sentinel key; never < LIMK

#define OFF_EXT  65536                  // 16*204*4 = 13056 B keys
#define SMEM_SZ  78592                  // 76.75 KB -> 2 blocks/CU

#define GLOAD_LDS16(gp, lp)                                            \
    __builtin_amdgcn_global_load_lds(                                  \
        (const __attribute__((address_space(1))) uint32_t*)(gp),       \
        (__attribute__((address_space(3))) uint32_t*)(lp), 16, 0, 0)

// ---- pre-pass kernel (fallback path): fp32 -> bf16 RNE ----
__global__ __launch_bounds__(1024) void conv_bf16(
    const float* __restrict__ w, uint16_t* __restrict__ o)
{
    const int i = (blockIdx.x * 1024 + threadIdx.x) * 4;   // 4 floats/thread
    if (i >= WS) return;
    const float4 f = *(const float4*)(w + i);
    uint32_t u0 = __float_as_uint(f.x), u1 = __float_as_uint(f.y);
    uint32_t u2 = __float_as_uint(f.z), u3 = __float_as_uint(f.w);
    ushort4 r;
    r.x = (uint16_t)((u0 + 0x7FFFu + ((u0 >> 16) & 1u)) >> 16);
    r.y = (uint16_t)((u1 + 0x7FFFu + ((u1 >> 16) & 1u)) >> 16);
    r.z = (uint16_t)((u2 + 0x7FFFu + ((u2 >> 16) & 1u)) >> 16);
    r.w = (uint16_t)((u3 + 0x7FFFu + ((u3 >> 16) & 1u)) >> 16);
    *(ushort4*)(o + i) = r;
}

// ---- shared sweep body (R16 structure + diff-routing + K-compare) ----
__device__ __forceinline__ void heb_body(
    uint8_t* smem,
    const uint16_t* __restrict__ wbf,
    const int*      __restrict__ indices,
    float*          __restrict__ out)
{
    const int tid     = threadIdx.x;
    const int d       = tid & 127;
    const int g       = tid >> 7;          // group 0..7 (pairs 2g, 2g+1)
    const int bagBase = blockIdx.x * BPB;

    uint16_t* tile0 = (uint16_t*)&smem[0];
    uint32_t* ext   = (uint32_t*)&smem[OFF_EXT];
    // sort scratch in tile region (dead before region-0 staging)
    uint32_t* araw  = (uint32_t*)&smem[0];        // [32][52] = 6656 B
    uint32_t* S     = (uint32_t*)&smem[6656];     // [32][52]

    // ---- phase 1: sentinel-fill ext; hash a = idx*P1 % WS ----
    for (int p = tid; p < NPAIR * EXTP; p += NTHR) ext[p] = SENT;
    for (int p = tid; p < BPB * BAG_LEN; p += NTHR) {
        uint32_t b = (uint32_t)p / 50u;
        uint32_t i = (uint32_t)p - b * 50u;
        uint64_t idx = (uint64_t)(uint32_t)
            indices[bagBase * BAG_LEN + p];
        araw[b * 52 + i] = (uint32_t)((idx * 9824516537ull) % (uint64_t)WS);
    }
    __syncthreads();

    // ---- phase 2a: rank-sort each bag (ties by index) -> S ----
    for (int p = tid; p < BPB * BAG_LEN; p += NTHR) {
        uint32_t b = (uint32_t)p / 50u;
        uint32_t i = (uint32_t)p - b * 50u;
        uint32_t v = araw[b * 52 + i];
        int rank = 0;
        for (int q = 0; q < BAG_LEN; ++q) {
            uint32_t w = araw[b * 52 + q];
            rank += (w < v || (w == v && q < (int)i)) ? 1 : 0;
        }
        S[b * 52 + rank] = v;
    }
    __syncthreads();

    // ---- phase 2b: 2-way merge per pair via one binary search ----
    for (int p = tid; p < BPB * BAG_LEN; p += NTHR) {
        uint32_t bag = (uint32_t)p / 50u;
        uint32_t i   = (uint32_t)p - bag * 50u;
        uint32_t pr  = bag >> 1, b = bag & 1u;
        uint32_t v = S[bag * 52 + i];
        const uint32_t* T = &S[(bag ^ 1u) * 52];
        uint32_t key = b ? v + 1u : v;         // tie-break by bag id
        int lo = 0, hi = 50;
        while (lo < hi) {                      // ~6 uniform steps
            int mid = (lo + hi) >> 1;
            bool lt = T[mid] < key;
            lo = lt ? mid + 1 : lo;
            hi = lt ? hi : mid;
        }
        uint32_t* eo = ext + pr * EXTP;
        int rk = (int)i + lo;
        eo[rk]       = (v << 1) | b;                    // first copy
        eo[rk + 100] = ((v + (uint32_t)WS) << 1) | b;   // rotation copy
    }
    __syncthreads();                       // ext final; scratch dead

    // ---- phase 3: per-thread 2-stream init (byte-offset state) ----
    const uint32_t c  = ((uint32_t)d * SBIG) % (uint32_t)WS;
    const uint32_t C2 = (uint32_t)(((int)c - WS) * 2);  // 2*(c-WS) mod 2^32
    const uint32_t limit2 = ((uint32_t)WS - c) << 1;    // keys < 2*(WS-c)

    uint32_t kb4[SPT], K4[SPT];
    float    saR[SPT], soR[SPT];
#pragma unroll
    for (int qi = 0; qi < SPT; ++qi) {
        const uint32_t rbase = (uint32_t)(g * SPT + qi) * EXTP;
        int lo = 0, hi = 100;
        while (lo < hi) {
            int mid = (lo + hi) >> 1;
            bool lt = ext[rbase + (uint32_t)mid] < limit2;
            lo = lt ? mid + 1 : lo;
            hi = lt ? hi : mid;
        }
        kb4[qi] = (uint32_t)OFF_EXT + ((rbase + (uint32_t)lo) << 2);
        K4[qi]  = ext[rbase + (uint32_t)lo];
        saR[qi] = 0.0f; soR[qi] = 0.0f;
    }

    // ---- phase 4: region sweep, single 64KB tile, 2 barriers/region ----
    for (int r = 0; r < NREGS; ++r) {
        const int rlo = r * TILEE;
        const int len = (TILEE < WS - rlo) ? TILEE : (WS - rlo);

        __syncthreads();                   // prev region consumed
        for (int s = tid; s < (len >> 3); s += NTHR)
            GLOAD_LDS16(wbf + rlo + (s << 3), tile0 + (s << 3));
        __syncthreads();                   // barrier drains vmcnt

        const uint32_t CLr  = C2 - ((uint32_t)rlo << 1);       // even
        const uint32_t LIMK = ((uint32_t)(len + rlo) << 1) - C2; // (0,8M]

#pragma unroll
        for (int qi = 0; qi < SPT; ++qi) {
            uint32_t kb = kb4[qi], K = K4[qi];
            float sa = saR[qi], so = soR[qi];
            while (K < LIMK) {             // condition direct on carried K
                const uint32_t a0  = (K & ~1u) + CLr;   // = u & ~1
                const uint32_t odd = K & 1u;
                const uint32_t raw =
                    *(const uint16_t*)(smem + a0);      // ds_read_u16
                kb += 4u;
                K = *(const uint32_t*)(smem + kb);      // next key (1 RT)
                const float v = __uint_as_float(raw << 16);
                sa += v;                                // diff-routing
                so += odd ? v : 0.0f;
            }
            kb4[qi] = kb; K4[qi] = K;
            saR[qi] = sa; soR[qi] = so;
        }
    }

    // ---- phase 5: output (bag even = sa - so, bag odd = so) ----
#pragma unroll
    for (int qi = 0; qi < SPT; ++qi) {
        const int bag = (g << 2) + (qi << 1);
        out[(size_t)(bagBase + bag) * EMB_DIM + d]     = saR[qi] - soR[qi];
        out[(size_t)(bagBase + bag + 1) * EMB_DIM + d] = soR[qi];
    }
}

// ---- non-cooperative sweep kernel (fallback path) ----
__global__ __launch_bounds__(NTHR, 8) void heb_bf16(
    const uint16_t* __restrict__ wbf,
    const int*      __restrict__ indices,
    float*          __restrict__ out)
{
    __shared__ __align__(16) uint8_t smem[SMEM_SZ];
    heb_body(smem, wbf, indices, out);
}

// ---- fused cooperative kernel: convert slice -> grid.sync -> sweep ----
__global__ __launch_bounds__(NTHR, 8) void heb_fused(
    const float*    __restrict__ w,
    uint16_t*       __restrict__ wbf,
    const int*      __restrict__ indices,
    float*          __restrict__ out)
{
    __shared__ __align__(16) uint8_t smem[SMEM_SZ];

    // phase 0: this block's fp32->bf16 slice (512*4096 >= 2M, WS%4==0)
    const int i = (blockIdx.x * NTHR + threadIdx.x) * 4;
    if (i < WS) {
        const float4 f = *(const float4*)(w + i);
        uint32_t u0 = __float_as_uint(f.x), u1 = __float_as_uint(f.y);
        uint32_t u2 = __float_as_uint(f.z), u3 = __float_as_uint(f.w);
        ushort4 r;
        r.x = (uint16_t)((u0 + 0x7FFFu + ((u0 >> 16) & 1u)) >> 16);
        r.y = (uint16_t)((u1 + 0x7FFFu + ((u1 >> 16) & 1u)) >> 16);
        r.z = (uint16_t)((u2 + 0x7FFFu + ((u2 >> 16) & 1u)) >> 16);
        r.w = (uint16_t)((u3 + 0x7FFFu + ((u3 >> 16) & 1u)) >> 16);
        *(ushort4*)(wbf + i) = r;
    }
    cg::this_grid().sync();               // all 512 blocks co-resident

    heb_body(smem, wbf, indices, out);
}

// ---- fallback (ws too small): R7's proven fp32 single-tile kernel ----
#define BAGS_FB  64
#define RSIZE_FB 32768
#define NREG_FB  62
#define EXT_N    104
#define SENT4    0x10000000u

__global__ __launch_bounds__(NTHR, 4) void heb_single(
    const float* __restrict__ weight,
    const int*   __restrict__ indices,
    float*       __restrict__ out)
{
    __shared__ __align__(16) float tile[RSIZE_FB];
    __shared__ uint32_t ext4[BAGS_FB][EXT_N];
    const int tid = threadIdx.x, d = tid & 127, bag_lo = tid >> 7;
    const int bagBase = blockIdx.x * BAGS_FB;
    uint32_t* araw = (uint32_t*)&tile[0];
    for (int p = tid; p < BAGS_FB * BAG_LEN; p += NTHR) {
        uint32_t g = (uint32_t)p / 50u, i = (uint32_t)p - g * 50u;
        uint64_t idx = (uint64_t)(uint32_t)indices[bagBase * BAG_LEN + p];
        araw[g * 52 + i] = (uint32_t)((idx * 9824516537ull) % (uint64_t)WS);
    }
    __syncthreads();
    for (int p = tid; p < BAGS_FB * BAG_LEN; p += NTHR) {
        uint32_t g = (uint32_t)p / 50u, i = (uint32_t)p - g * 50u;
        uint32_t v = araw[g * 52 + i];
        int rank = 0;
        for (int q = 0; q < BAG_LEN; ++q) {
            uint32_t w = araw[g * 52 + q];
            rank += (w < v || (w == v && q < (int)i)) ? 1 : 0;
        }
        ext4[g][rank] = v << 2;
        ext4[g][rank + 50] = (v + (uint32_t)WS) << 2;
    }
    for (int p = tid; p < BAGS_FB * 4; p += NTHR)
        ext4[p >> 2][100 + (p & 3)] = SENT4;
    __syncthreads();
    const uint32_t c = ((uint32_t)d * SBIG) % (uint32_t)WS;
    const uint32_t C4 = (uint32_t)(((int)c - WS) * 4);
    const uint32_t wmc4 = ((uint32_t)WS - c) << 2;
    uint32_t t4[8], h4[8]; float sm[8];
#pragma unroll
    for (int k = 0; k < 8; ++k) {
        const uint32_t* eg = &ext4[(bag_lo << 3) + k][0];
        int nlow = 0;
        for (int q = 0; q < BAG_LEN; ++q) nlow += (eg[q] < wmc4) ? 1 : 0;
        t4[k] = (uint32_t)nlow << 2; h4[k] = eg[nlow] + C4; sm[k] = 0.0f;
    }
    for (int r = 0; r < NREG_FB; ++r) {
        const int lo = r * RSIZE_FB;
        const int len = (RSIZE_FB < WS - lo) ? RSIZE_FB : (WS - lo);
        __syncthreads();
        for (int s = tid; s < (len >> 2); s += NTHR)
            GLOAD_LDS16(weight + lo + (s << 2), &tile[s << 2]);
        __syncthreads();
        const uint32_t lo4 = ((uint32_t)lo) << 2;
        const uint32_t hi4 = (r == NREG_FB - 1) ? (uint32_t)(4 * WS)
                                                : lo4 + ((uint32_t)RSIZE_FB << 2);
        const char* tb = (const char*)&tile[0];
#pragma unroll
        for (int k = 0; k < 8; ++k) {
            const char* eg = (const char*)&ext4[(bag_lo << 3) + k][0];
            uint32_t t_ = t4[k], h_ = h4[k]; float s_ = sm[k];
            while (h_ < hi4) {
                s_ += *(const float*)(tb + (h_ - lo4));
                t_ += 4u;
                h_ = *(const uint32_t*)(eg + t_) + C4;
            }
            t4[k] = t_; h4[k] = h_; sm[k] = s_;
        }
    }
#pragma unroll
    for (int k = 0; k < 8; ++k)
        out[(size_t)(bagBase + (bag_lo << 3) + k) * EMB_DIM + d] = sm[k];
}

extern "C" void kernel_launch(void* const* d_in, const int* in_sizes, int n_in,
                              void* d_out, int out_size, void* d_ws, size_t ws_size,
                              hipStream_t stream)
{
    const float* weight  = (const float*)d_in[0];   // [2,000,000] fp32
    const int*   indices = (const int*)d_in[1];     // [16384*50] int
    float*       out     = (float*)d_out;           // [16384*128] fp32

    if (ws_size >= (size_t)WS * sizeof(uint16_t)) {
        uint16_t* wbf = (uint16_t*)d_ws;
        void* args[] = { (void*)&weight, (void*)&wbf,
                         (void*)&indices, (void*)&out };
        hipError_t e = hipLaunchCooperativeKernel(
            reinterpret_cast<void*>(heb_fused),
            dim3(NBLK), dim3(NTHR), args, 0, stream);
        if (e != hipSuccess) {
            // fallback: proven two-kernel path (conv + sweep)
            conv_bf16<<<(WS / 4 + 1023) / 1024, 1024, 0, stream>>>(weight, wbf);
            heb_bf16<<<NBLK, NTHR, 0, stream>>>(wbf, indices, out);
        }
    } else {
        heb_single<<<256, NTHR, 0, stream>>>(weight, indices, out);
    }
}

// Round 11
// 212.045 us; speedup vs baseline: 1.2549x; 1.2549x over previous
//
#include <hip/hip_runtime.h>
#include <stdint.h>

// HashedEmbeddingBag: out[b][d] = sum_{i<50} weight[(idx[b][i]*P1 + d*P2) % WS]
// WS = 2,000,000; B = 16384; L = 50; D = 128.
//
// R20: REVERT to R16 verbatim -- the measured optimum (163.8us kernel /
// 210.5us total, VALU 87%, occ 76%).
// Ledger: nine structural variations off R16 all regressed or were
// neutral: merge degree (R9 177 / R12 181), unrolls (R13 183 neutral,
// R17 233 broken pipeline, R18 174.5 select-chained), LDS-atomic accum
// (R10/R11 670 -- ds_add_f32 ~15x a ds_read, never in hot path),
// in-block hybrid (R14 188, shared barrier = shared critical path),
// grid-split hybrid (R15 207, E[max] inflation + exposed staging),
// coop fusion + trims (R19 ~202 -- smem through a function parameter
// broke addrspace lowering, R10-class latency signature; and fusing
// launches RAISED total, so the ~47us total-vs-kernel gap is
// harness-fixed, not kernel-addressable).
// R16's winning properties, all preserved EXACTLY:
//  - 2 blocks/CU (76.75KB smem), 8 waves/SIMD: the R16 TLP fix
//    (181->163.8, VALU 66->87%) -- latency-bound confirmed and cured.
//  - inner loop: 1 key ds_read RT/iter carried chain (software-pipelined
//    by construction: gather addr uses the PREVIOUS iteration's key);
//    local __shared__ casts -> guaranteed ds_ addressing.
//  - 512 blocks x 32 bags, 16 pair-merged streams, SPT=2, keys
//    (v<<1)|b + rotation copy + 4 sentinels; 64KB tile, 62 regions,
//    2 barriers/region; register accumulators; coalesced output.
// At this point VALU ~87% and LDS ~85% are jointly near-saturated, HBM
// idle by design: dual-pipe saturation floor of this algorithm family.
// Accuracy: bf16 RNE table, pair-order register sums (absmax 0.25,
// threshold 0.71).

#define WS       2000000
#define EMB_DIM  128
#define BAG_LEN  50
#define BATCH    16384

#define NBLK     512
#define NTHR     1024
#define BPB      32                     // bags per block
#define NPAIR    16                     // bag-pair streams per block
#define SPT      2                      // streams per thread
#define EXTP     204                    // 100 + 100 rotation + 4 sentinels
#define TILEE    32768                  // tile entries (bf16) = 64KB
#define NREGS    62                     // 61*32768=1,998,848; last 1152
#define SBIG     300227u                // P2 % WS
#define SENT     0x10000000u            // sentinel key; u stays >= LIM

#define OFF_EXT  65536                  // 16*204*4 = 13056 B keys
#define SMEM_SZ  78592                  // 76.75 KB -> 2 blocks/CU

#define GLOAD_LDS16(gp, lp)                                            \
    __builtin_amdgcn_global_load_lds(                                  \
        (const __attribute__((address_space(1))) uint32_t*)(gp),       \
        (__attribute__((address_space(3))) uint32_t*)(lp), 16, 0, 0)

// ---- pre-pass: fp32 table -> bf16 (round-to-nearest-even) ----
__global__ __launch_bounds__(1024) void conv_bf16(
    const float* __restrict__ w, uint16_t* __restrict__ o)
{
    const int i = (blockIdx.x * 1024 + threadIdx.x) * 4;   // 4 floats/thread
    if (i >= WS) return;
    const float4 f = *(const float4*)(w + i);
    uint32_t u0 = __float_as_uint(f.x), u1 = __float_as_uint(f.y);
    uint32_t u2 = __float_as_uint(f.z), u3 = __float_as_uint(f.w);
    ushort4 r;
    r.x = (uint16_t)((u0 + 0x7FFFu + ((u0 >> 16) & 1u)) >> 16);
    r.y = (uint16_t)((u1 + 0x7FFFu + ((u1 >> 16) & 1u)) >> 16);
    r.z = (uint16_t)((u2 + 0x7FFFu + ((u2 >> 16) & 1u)) >> 16);
    r.w = (uint16_t)((u3 + 0x7FFFu + ((u3 >> 16) & 1u)) >> 16);
    *(ushort4*)(o + i) = r;
}

__global__ __launch_bounds__(NTHR, 8) void heb_bf16(
    const uint16_t* __restrict__ wbf,
    const int*      __restrict__ indices,
    float*          __restrict__ out)
{
    __shared__ __align__(16) uint8_t smem[SMEM_SZ];

    const int tid     = threadIdx.x;
    const int d       = tid & 127;
    const int g       = tid >> 7;          // group 0..7 (pairs 2g, 2g+1)
    const int bagBase = blockIdx.x * BPB;

    uint16_t* tile0 = (uint16_t*)&smem[0];
    uint32_t* ext   = (uint32_t*)&smem[OFF_EXT];
    // sort scratch in tile region (dead before region-0 staging, which
    // happens only after the phase-3 barrier)
    uint32_t* araw  = (uint32_t*)&smem[0];        // [32][52] = 6656 B
    uint32_t* S     = (uint32_t*)&smem[6656];     // [32][52]

    // ---- phase 1: sentinel-fill ext; hash a = idx*P1 % WS ----
    for (int p = tid; p < NPAIR * EXTP; p += NTHR) ext[p] = SENT;
    for (int p = tid; p < BPB * BAG_LEN; p += NTHR) {
        uint32_t b = (uint32_t)p / 50u;
        uint32_t i = (uint32_t)p - b * 50u;
        uint64_t idx = (uint64_t)(uint32_t)
            indices[bagBase * BAG_LEN + p];
        araw[b * 52 + i] = (uint32_t)((idx * 9824516537ull) % (uint64_t)WS);
    }
    __syncthreads();

    // ---- phase 2a: rank-sort each bag (ties by index) -> S ----
    for (int p = tid; p < BPB * BAG_LEN; p += NTHR) {
        uint32_t b = (uint32_t)p / 50u;
        uint32_t i = (uint32_t)p - b * 50u;
        uint32_t v = araw[b * 52 + i];
        int rank = 0;
        for (int q = 0; q < BAG_LEN; ++q) {
            uint32_t w = araw[b * 52 + q];
            rank += (w < v || (w == v && q < (int)i)) ? 1 : 0;
        }
        S[b * 52 + rank] = v;
    }
    __syncthreads();

    // ---- phase 2b: 2-way merge per pair via one binary search ----
    for (int p = tid; p < BPB * BAG_LEN; p += NTHR) {
        uint32_t bag = (uint32_t)p / 50u;
        uint32_t i   = (uint32_t)p - bag * 50u;
        uint32_t pr  = bag >> 1, b = bag & 1u;
        uint32_t v = S[bag * 52 + i];
        const uint32_t* T = &S[(bag ^ 1u) * 52];
        uint32_t key = b ? v + 1u : v;         // tie-break by bag id
        int lo = 0, hi = 50;
        while (lo < hi) {                      // ~6 uniform steps
            int mid = (lo + hi) >> 1;
            bool lt = T[mid] < key;
            lo = lt ? mid + 1 : lo;
            hi = lt ? hi : mid;
        }
        uint32_t* eo = ext + pr * EXTP;
        int rk = (int)i + lo;
        eo[rk]       = (v << 1) | b;                    // first copy
        eo[rk + 100] = ((v + (uint32_t)WS) << 1) | b;   // rotation copy
    }
    __syncthreads();                       // ext final; scratch dead

    // ---- phase 3: per-thread 2-stream init (word-index state) ----
    const uint32_t c  = ((uint32_t)d * SBIG) % (uint32_t)WS;
    const uint32_t C2 = (uint32_t)(((int)c - WS) * 2);  // 2*(c-WS) mod 2^32
    const uint32_t limit2 = ((uint32_t)WS - c) << 1;    // keys < 2*(WS-c)

    uint32_t kq4[SPT], K4[SPT];
    float    s0r[SPT], s1r[SPT];
#pragma unroll
    for (int qi = 0; qi < SPT; ++qi) {
        const uint32_t rbase = (uint32_t)(g * SPT + qi) * EXTP;
        int lo = 0, hi = 100;
        while (lo < hi) {
            int mid = (lo + hi) >> 1;
            bool lt = ext[rbase + (uint32_t)mid] < limit2;
            lo = lt ? mid + 1 : lo;
            hi = lt ? hi : mid;
        }
        kq4[qi] = rbase + (uint32_t)lo;    // absolute word index into ext
        K4[qi]  = ext[rbase + (uint32_t)lo];
        s0r[qi] = 0.0f; s1r[qi] = 0.0f;
    }

    // ---- phase 4: region sweep, single 64KB tile, 2 barriers/region ----
    for (int r = 0; r < NREGS; ++r) {
        const int rlo = r * TILEE;
        const int len = (TILEE < WS - rlo) ? TILEE : (WS - rlo);

        __syncthreads();                   // prev region consumed
        for (int s = tid; s < (len >> 3); s += NTHR)
            GLOAD_LDS16(wbf + rlo + (s << 3), tile0 + (s << 3));
        __syncthreads();                   // barrier drains vmcnt

        const uint32_t CLr = C2 - ((uint32_t)rlo << 1);
        const uint32_t LIM = (uint32_t)len << 1;

#pragma unroll
        for (int qi = 0; qi < SPT; ++qi) {
            uint32_t kq = kq4[qi], K = K4[qi];
            float s0 = s0r[qi], s1 = s1r[qi];
            uint32_t u = K + CLr;          // 2*(pos-rlo) + tag
            while (u < LIM) {
                const uint32_t raw =
                    *(const uint16_t*)(smem + (u & ~1u)); // ds_read_u16
                K = ext[kq + 1u];                  // next key early
                ++kq;
                const float v = __uint_as_float(raw << 16);
                const bool odd = (u & 1u) != 0u;   // 1-bit routing
                s0 += odd ? 0.0f : v;
                s1 += odd ? v : 0.0f;
                u = K + CLr;
            }
            kq4[qi] = kq; K4[qi] = K;
            s0r[qi] = s0; s1r[qi] = s1;
        }
    }

    // ---- phase 5: output straight from registers (bag = 4g + 2qi + t) ----
#pragma unroll
    for (int qi = 0; qi < SPT; ++qi) {
        const int bag = (g << 2) + (qi << 1);
        out[(size_t)(bagBase + bag) * EMB_DIM + d]     = s0r[qi];
        out[(size_t)(bagBase + bag + 1) * EMB_DIM + d] = s1r[qi];
    }
}

// ---- fallback (ws too small): R7's proven fp32 single-tile kernel ----
#define BAGS_FB  64
#define RSIZE_FB 32768
#define NREG_FB  62
#define EXT_N    104
#define SENT4    0x10000000u

__global__ __launch_bounds__(NTHR, 4) void heb_single(
    const float* __restrict__ weight,
    const int*   __restrict__ indices,
    float*       __restrict__ out)
{
    __shared__ __align__(16) float tile[RSIZE_FB];
    __shared__ uint32_t ext4[BAGS_FB][EXT_N];
    const int tid = threadIdx.x, d = tid & 127, bag_lo = tid >> 7;
    const int bagBase = blockIdx.x * BAGS_FB;
    uint32_t* araw = (uint32_t*)&tile[0];
    for (int p = tid; p < BAGS_FB * BAG_LEN; p += NTHR) {
        uint32_t g = (uint32_t)p / 50u, i = (uint32_t)p - g * 50u;
        uint64_t idx = (uint64_t)(uint32_t)indices[bagBase * BAG_LEN + p];
        araw[g * 52 + i] = (uint32_t)((idx * 9824516537ull) % (uint64_t)WS);
    }
    __syncthreads();
    for (int p = tid; p < BAGS_FB * BAG_LEN; p += NTHR) {
        uint32_t g = (uint32_t)p / 50u, i = (uint32_t)p - g * 50u;
        uint32_t v = araw[g * 52 + i];
        int rank = 0;
        for (int q = 0; q < BAG_LEN; ++q) {
            uint32_t w = araw[g * 52 + q];
            rank += (w < v || (w == v && q < (int)i)) ? 1 : 0;
        }
        ext4[g][rank] = v << 2;
        ext4[g][rank + 50] = (v + (uint32_t)WS) << 2;
    }
    for (int p = tid; p < BAGS_FB * 4; p += NTHR)
        ext4[p >> 2][100 + (p & 3)] = SENT4;
    __syncthreads();
    const uint32_t c = ((uint32_t)d * SBIG) % (uint32_t)WS;
    const uint32_t C4 = (uint32_t)(((int)c - WS) * 4);
    const uint32_t wmc4 = ((uint32_t)WS - c) << 2;
    uint32_t t4[8], h4[8]; float sm[8];
#pragma unroll
    for (int k = 0; k < 8; ++k) {
        const uint32_t* eg = &ext4[(bag_lo << 3) + k][0];
        int nlow = 0;
        for (int q = 0; q < BAG_LEN; ++q) nlow += (eg[q] < wmc4) ? 1 : 0;
        t4[k] = (uint32_t)nlow << 2; h4[k] = eg[nlow] + C4; sm[k] = 0.0f;
    }
    for (int r = 0; r < NREG_FB; ++r) {
        const int lo = r * RSIZE_FB;
        const int len = (RSIZE_FB < WS - lo) ? RSIZE_FB : (WS - lo);
        __syncthreads();
        for (int s = tid; s < (len >> 2); s += NTHR)
            GLOAD_LDS16(weight + lo + (s << 2), &tile[s << 2]);
        __syncthreads();
        const uint32_t lo4 = ((uint32_t)lo) << 2;
        const uint32_t hi4 = (r == NREG_FB - 1) ? (uint32_t)(4 * WS)
                                                : lo4 + ((uint32_t)RSIZE_FB << 2);
        const char* tb = (const char*)&tile[0];
#pragma unroll
        for (int k = 0; k < 8; ++k) {
            const char* eg = (const char*)&ext4[(bag_lo << 3) + k][0];
            uint32_t t_ = t4[k], h_ = h4[k]; float s_ = sm[k];
            while (h_ < hi4) {
                s_ += *(const float*)(tb + (h_ - lo4));
                t_ += 4u;
                h_ = *(const uint32_t*)(eg + t_) + C4;
            }
            t4[k] = t_; h4[k] = h_; sm[k] = s_;
        }
    }
#pragma unroll
    for (int k = 0; k < 8; ++k)
        out[(size_t)(bagBase + (bag_lo << 3) + k) * EMB_DIM + d] = sm[k];
}

extern "C" void kernel_launch(void* const* d_in, const int* in_sizes, int n_in,
                              void* d_out, int out_size, void* d_ws, size_t ws_size,
                              hipStream_t stream)
{
    const float* weight  = (const float*)d_in[0];   // [2,000,000] fp32
    const int*   indices = (const int*)d_in[1];     // [16384*50] int
    float*       out     = (float*)d_out;           // [16384*128] fp32

    if (ws_size >= (size_t)WS * sizeof(uint16_t)) {
        uint16_t* wbf = (uint16_t*)d_ws;
        conv_bf16<<<(WS / 4 + 1023) / 1024, 1024, 0, stream>>>(weight, wbf);
        heb_bf16<<<NBLK, NTHR, 0, stream>>>(wbf, indices, out);
    } else {
        heb_single<<<256, NTHR, 0, stream>>>(weight, indices, out);
    }
}

// Round 12
// 211.486 us; speedup vs baseline: 1.2582x; 1.0026x over previous
//
#include <hip/hip_runtime.h>
#include <stdint.h>

// HashedEmbeddingBag: out[b][d] = sum_{i<50} weight[(idx[b][i]*P1 + d*P2) % WS]
// WS = 2,000,000; B = 16384; L = 50; D = 128.
//
// R21: R16/R20 body (reproduced twice: 163.8/163.3us, VALU 87%, occ 76%)
// with ONLY the two R17-proven trims, finally isolated:
//  - diff-routing: sa += v; so += (K&1)?v:0; epilogue even = sa - so.
//    (saves ~2 VALU/elem off the ~12-op body; accumulate-only, not in
//    the carried chain; f32 cancellation ~1e-6 rel, invisible under the
//    accepted 0.25 bf16 absmax, threshold 0.71 -- proven R17/R18.)
//  - K-space condition: while (K < LIMK), LIMK = 2*(len+rlo) - C2 in
//    (0,8M]; sentinel 0x10000000 (268M) never passes; gather addr
//    (K&~1)+CLr == (u&~1) since CLr is even. Removes the u=K+CLr add
//    from the loop-control chain. (Proven R17/R18.)
// These were previously confounded: R17 welded them to a broken-pipeline
// unroll (233us), R18 to a select-chained unroll (174.5us), R19 to the
// heb_body smem-parameter refactor that destroyed LDS addrspace lowering
// (~202us). This round: R20 source byte-identical except the loop
// condition, two accumulate lines, and the epilogue -- local __shared__,
// two-kernel path, 1-key-RT/iter pipeline all preserved.
// Floor model: LDS pipe ~347K cy/CU (~89%) vs VALU ~87%; trims shave
// VALU only -> gain bounded by LDS floor (~148-152us). Predict 156-161us;
// pre-committed: flat/regression -> <<ROOFLINE>> next round.
// Geometry (R16-proven): 512 blocks x 32 bags, 16 pair-merged streams,
// SPT=2, 64KB tile, 62 regions, 76.75KB smem -> 2 blocks/CU, 8 w/SIMD.

#define WS       2000000
#define EMB_DIM  128
#define BAG_LEN  50
#define BATCH    16384

#define NBLK     512
#define NTHR     1024
#define BPB      32                     // bags per block
#define NPAIR    16                     // bag-pair streams per block
#define SPT      2                      // streams per thread
#define EXTP     204                    // 100 + 100 rotation + 4 sentinels
#define TILEE    32768                  // tile entries (bf16) = 64KB
#define NREGS    62                     // 61*32768=1,998,848; last 1152
#define SBIG     300227u                // P2 % WS
#define SENT     0x10000000u            // sentinel key; never < LIMK

#define OFF_EXT  65536                  // 16*204*4 = 13056 B keys
#define SMEM_SZ  78592                  // 76.75 KB -> 2 blocks/CU

#define GLOAD_LDS16(gp, lp)                                            \
    __builtin_amdgcn_global_load_lds(                                  \
        (const __attribute__((address_space(1))) uint32_t*)(gp),       \
        (__attribute__((address_space(3))) uint32_t*)(lp), 16, 0, 0)

// ---- pre-pass: fp32 table -> bf16 (round-to-nearest-even) ----
__global__ __launch_bounds__(1024) void conv_bf16(
    const float* __restrict__ w, uint16_t* __restrict__ o)
{
    const int i = (blockIdx.x * 1024 + threadIdx.x) * 4;   // 4 floats/thread
    if (i >= WS) return;
    const float4 f = *(const float4*)(w + i);
    uint32_t u0 = __float_as_uint(f.x), u1 = __float_as_uint(f.y);
    uint32_t u2 = __float_as_uint(f.z), u3 = __float_as_uint(f.w);
    ushort4 r;
    r.x = (uint16_t)((u0 + 0x7FFFu + ((u0 >> 16) & 1u)) >> 16);
    r.y = (uint16_t)((u1 + 0x7FFFu + ((u1 >> 16) & 1u)) >> 16);
    r.z = (uint16_t)((u2 + 0x7FFFu + ((u2 >> 16) & 1u)) >> 16);
    r.w = (uint16_t)((u3 + 0x7FFFu + ((u3 >> 16) & 1u)) >> 16);
    *(ushort4*)(o + i) = r;
}

__global__ __launch_bounds__(NTHR, 8) void heb_bf16(
    const uint16_t* __restrict__ wbf,
    const int*      __restrict__ indices,
    float*          __restrict__ out)
{
    __shared__ __align__(16) uint8_t smem[SMEM_SZ];

    const int tid     = threadIdx.x;
    const int d       = tid & 127;
    const int g       = tid >> 7;          // group 0..7 (pairs 2g, 2g+1)
    const int bagBase = blockIdx.x * BPB;

    uint16_t* tile0 = (uint16_t*)&smem[0];
    uint32_t* ext   = (uint32_t*)&smem[OFF_EXT];
    // sort scratch in tile region (dead before region-0 staging, which
    // happens only after the phase-3 barrier)
    uint32_t* araw  = (uint32_t*)&smem[0];        // [32][52] = 6656 B
    uint32_t* S     = (uint32_t*)&smem[6656];     // [32][52]

    // ---- phase 1: sentinel-fill ext; hash a = idx*P1 % WS ----
    for (int p = tid; p < NPAIR * EXTP; p += NTHR) ext[p] = SENT;
    for (int p = tid; p < BPB * BAG_LEN; p += NTHR) {
        uint32_t b = (uint32_t)p / 50u;
        uint32_t i = (uint32_t)p - b * 50u;
        uint64_t idx = (uint64_t)(uint32_t)
            indices[bagBase * BAG_LEN + p];
        araw[b * 52 + i] = (uint32_t)((idx * 9824516537ull) % (uint64_t)WS);
    }
    __syncthreads();

    // ---- phase 2a: rank-sort each bag (ties by index) -> S ----
    for (int p = tid; p < BPB * BAG_LEN; p += NTHR) {
        uint32_t b = (uint32_t)p / 50u;
        uint32_t i = (uint32_t)p - b * 50u;
        uint32_t v = araw[b * 52 + i];
        int rank = 0;
        for (int q = 0; q < BAG_LEN; ++q) {
            uint32_t w = araw[b * 52 + q];
            rank += (w < v || (w == v && q < (int)i)) ? 1 : 0;
        }
        S[b * 52 + rank] = v;
    }
    __syncthreads();

    // ---- phase 2b: 2-way merge per pair via one binary search ----
    for (int p = tid; p < BPB * BAG_LEN; p += NTHR) {
        uint32_t bag = (uint32_t)p / 50u;
        uint32_t i   = (uint32_t)p - bag * 50u;
        uint32_t pr  = bag >> 1, b = bag & 1u;
        uint32_t v = S[bag * 52 + i];
        const uint32_t* T = &S[(bag ^ 1u) * 52];
        uint32_t key = b ? v + 1u : v;         // tie-break by bag id
        int lo = 0, hi = 50;
        while (lo < hi) {                      // ~6 uniform steps
            int mid = (lo + hi) >> 1;
            bool lt = T[mid] < key;
            lo = lt ? mid + 1 : lo;
            hi = lt ? hi : mid;
        }
        uint32_t* eo = ext + pr * EXTP;
        int rk = (int)i + lo;
        eo[rk]       = (v << 1) | b;                    // first copy
        eo[rk + 100] = ((v + (uint32_t)WS) << 1) | b;   // rotation copy
    }
    __syncthreads();                       // ext final; scratch dead

    // ---- phase 3: per-thread 2-stream init (word-index state) ----
    const uint32_t c  = ((uint32_t)d * SBIG) % (uint32_t)WS;
    const uint32_t C2 = (uint32_t)(((int)c - WS) * 2);  // 2*(c-WS) mod 2^32
    const uint32_t limit2 = ((uint32_t)WS - c) << 1;    // keys < 2*(WS-c)

    uint32_t kq4[SPT], K4[SPT];
    float    saR[SPT], soR[SPT];
#pragma unroll
    for (int qi = 0; qi < SPT; ++qi) {
        const uint32_t rbase = (uint32_t)(g * SPT + qi) * EXTP;
        int lo = 0, hi = 100;
        while (lo < hi) {
            int mid = (lo + hi) >> 1;
            bool lt = ext[rbase + (uint32_t)mid] < limit2;
            lo = lt ? mid + 1 : lo;
            hi = lt ? hi : mid;
        }
        kq4[qi] = rbase + (uint32_t)lo;    // absolute word index into ext
        K4[qi]  = ext[rbase + (uint32_t)lo];
        saR[qi] = 0.0f; soR[qi] = 0.0f;
    }

    // ---- phase 4: region sweep, single 64KB tile, 2 barriers/region ----
    for (int r = 0; r < NREGS; ++r) {
        const int rlo = r * TILEE;
        const int len = (TILEE < WS - rlo) ? TILEE : (WS - rlo);

        __syncthreads();                   // prev region consumed
        for (int s = tid; s < (len >> 3); s += NTHR)
            GLOAD_LDS16(wbf + rlo + (s << 3), tile0 + (s << 3));
        __syncthreads();                   // barrier drains vmcnt

        const uint32_t CLr  = C2 - ((uint32_t)rlo << 1);         // even
        const uint32_t LIMK = ((uint32_t)(len + rlo) << 1) - C2; // (0,8M]

#pragma unroll
        for (int qi = 0; qi < SPT; ++qi) {
            uint32_t kq = kq4[qi], K = K4[qi];
            float sa = saR[qi], so = soR[qi];
            while (K < LIMK) {             // condition direct on carried K
                const uint32_t a0  = (K & ~1u) + CLr;   // == u & ~1
                const uint32_t odd = K & 1u;
                const uint32_t raw =
                    *(const uint16_t*)(smem + a0);      // ds_read_u16
                K = ext[kq + 1u];                  // next key early (1 RT)
                ++kq;
                const float v = __uint_as_float(raw << 16);
                sa += v;                                // diff-routing
                so += odd ? v : 0.0f;
            }
            kq4[qi] = kq; K4[qi] = K;
            saR[qi] = sa; soR[qi] = so;
        }
    }

    // ---- phase 5: output (bag even = sa - so, bag odd = so) ----
#pragma unroll
    for (int qi = 0; qi < SPT; ++qi) {
        const int bag = (g << 2) + (qi << 1);
        out[(size_t)(bagBase + bag) * EMB_DIM + d]     = saR[qi] - soR[qi];
        out[(size_t)(bagBase + bag + 1) * EMB_DIM + d] = soR[qi];
    }
}

// ---- fallback (ws too small): R7's proven fp32 single-tile kernel ----
#define BAGS_FB  64
#define RSIZE_FB 32768
#define NREG_FB  62
#define EXT_N    104
#define SENT4    0x10000000u

__global__ __launch_bounds__(NTHR, 4) void heb_single(
    const float* __restrict__ weight,
    const int*   __restrict__ indices,
    float*       __restrict__ out)
{
    __shared__ __align__(16) float tile[RSIZE_FB];
    __shared__ uint32_t ext4[BAGS_FB][EXT_N];
    const int tid = threadIdx.x, d = tid & 127, bag_lo = tid >> 7;
    const int bagBase = blockIdx.x * BAGS_FB;
    uint32_t* araw = (uint32_t*)&tile[0];
    for (int p = tid; p < BAGS_FB * BAG_LEN; p += NTHR) {
        uint32_t g = (uint32_t)p / 50u, i = (uint32_t)p - g * 50u;
        uint64_t idx = (uint64_t)(uint32_t)indices[bagBase * BAG_LEN + p];
        araw[g * 52 + i] = (uint32_t)((idx * 9824516537ull) % (uint64_t)WS);
    }
    __syncthreads();
    for (int p = tid; p < BAGS_FB * BAG_LEN; p += NTHR) {
        uint32_t g = (uint32_t)p / 50u, i = (uint32_t)p - g * 50u;
        uint32_t v = araw[g * 52 + i];
        int rank = 0;
        for (int q = 0; q < BAG_LEN; ++q) {
            uint32_t w = araw[g * 52 + q];
            rank += (w < v || (w == v && q < (int)i)) ? 1 : 0;
        }
        ext4[g][rank] = v << 2;
        ext4[g][rank + 50] = (v + (uint32_t)WS) << 2;
    }
    for (int p = tid; p < BAGS_FB * 4; p += NTHR)
        ext4[p >> 2][100 + (p & 3)] = SENT4;
    __syncthreads();
    const uint32_t c = ((uint32_t)d * SBIG) % (uint32_t)WS;
    const uint32_t C4 = (uint32_t)(((int)c - WS) * 4);
    const uint32_t wmc4 = ((uint32_t)WS - c) << 2;
    uint32_t t4[8], h4[8]; float sm[8];
#pragma unroll
    for (int k = 0; k < 8; ++k) {
        const uint32_t* eg = &ext4[(bag_lo << 3) + k][0];
        int nlow = 0;
        for (int q = 0; q < BAG_LEN; ++q) nlow += (eg[q] < wmc4) ? 1 : 0;
        t4[k] = (uint32_t)nlow << 2; h4[k] = eg[nlow] + C4; sm[k] = 0.0f;
    }
    for (int r = 0; r < NREG_FB; ++r) {
        const int lo = r * RSIZE_FB;
        const int len = (RSIZE_FB < WS - lo) ? RSIZE_FB : (WS - lo);
        __syncthreads();
        for (int s = tid; s < (len >> 2); s += NTHR)
            GLOAD_LDS16(weight + lo + (s << 2), &tile[s << 2]);
        __syncthreads();
        const uint32_t lo4 = ((uint32_t)lo) << 2;
        const uint32_t hi4 = (r == NREG_FB - 1) ? (uint32_t)(4 * WS)
                                                : lo4 + ((uint32_t)RSIZE_FB << 2);
        const char* tb = (const char*)&tile[0];
#pragma unroll
        for (int k = 0; k < 8; ++k) {
            const char* eg = (const char*)&ext4[(bag_lo << 3) + k][0];
            uint32_t t_ = t4[k], h_ = h4[k]; float s_ = sm[k];
            while (h_ < hi4) {
                s_ += *(const float*)(tb + (h_ - lo4));
                t_ += 4u;
                h_ = *(const uint32_t*)(eg + t_) + C4;
            }
            t4[k] = t_; h4[k] = h_; sm[k] = s_;
        }
    }
#pragma unroll
    for (int k = 0; k < 8; ++k)
        out[(size_t)(bagBase + (bag_lo << 3) + k) * EMB_DIM + d] = sm[k];
}

extern "C" void kernel_launch(void* const* d_in, const int* in_sizes, int n_in,
                              void* d_out, int out_size, void* d_ws, size_t ws_size,
                              hipStream_t stream)
{
    const float* weight  = (const float*)d_in[0];   // [2,000,000] fp32
    const int*   indices = (const int*)d_in[1];     // [16384*50] int
    float*       out     = (float*)d_out;           // [16384*128] fp32

    if (ws_size >= (size_t)WS * sizeof(uint16_t)) {
        uint16_t* wbf = (uint16_t*)d_ws;
        conv_bf16<<<(WS / 4 + 1023) / 1024, 1024, 0, stream>>>(weight, wbf);
        heb_bf16<<<NBLK, NTHR, 0, stream>>>(wbf, indices, out);
    } else {
        heb_single<<<256, NTHR, 0, stream>>>(weight, indices, out);
    }
}